// Round 4
// baseline (224.257 us; speedup 1.0000x reference)
//
#include <hip/hip_runtime.h>

typedef unsigned short u16;
typedef __bf16 bf16x8 __attribute__((ext_vector_type(8)));
typedef float f32x4 __attribute__((ext_vector_type(4)));

#define MFMA(a, b, c) __builtin_amdgcn_mfma_f32_16x16x32_bf16((a), (b), (c), 0, 0, 0)

__device__ __forceinline__ u16 f2bf(float f) {
    unsigned u = __float_as_uint(f);
    unsigned r = (u + 0x7fffu + ((u >> 16) & 1u)) >> 16;  // RNE
    return (u16)r;
}
__device__ __forceinline__ float bf2f(u16 h) { return __uint_as_float(((unsigned)h) << 16); }

typedef unsigned int u32_g __attribute__((address_space(1)));
typedef unsigned int u32_l __attribute__((address_space(3)));
__device__ __forceinline__ void gload16(const void* g, void* l) {
    __builtin_amdgcn_global_load_lds((const u32_g*)g, (u32_l*)l, 16, 0, 0);
}

// ---------------------------------------------------------------------------
// Shapes: b=16, c=256, n=4096, heads=8, dim_head=32
// Gram-trick pipeline: everything n-sized collapses through G = X.X^T (256x256/b)
// ---------------------------------------------------------------------------

// K1 v2: LayerNorm, register-resident. x (b,c,n) fp32 -> xlnT (b,n,c) bf16 AND xcn (b,c,n) bf16
// 32 n per block, grid = 16*128 = 2048. Thread (np, cg): n-pair np (2 n), c-group cg (16 c).
__global__ __launch_bounds__(256) void k_ln(const float* __restrict__ x,
                                            const float* __restrict__ gamma,
                                            const float* __restrict__ beta,
                                            u16* __restrict__ xlnT, u16* __restrict__ xcn) {
    int bid = blockIdx.x;
    int b = bid >> 7, nt = bid & 127;
    int nb = nt * 32;
    __shared__ float redS[32 * 17], redS2[32 * 17];  // [n_local][cg] pad 17
    __shared__ float muv[32], rsv[32];
    __shared__ float gs[256], es[256];
    __shared__ unsigned xst[256 * 17];               // [c][np] packed (n0,n1) pairs, pad 17
    int t = threadIdx.x;
    int np = t & 15, cg = t >> 4;
    gs[t] = gamma[t];
    es[t] = beta[t];
    const float* xp = x + ((size_t)(b * 256 + cg * 16)) * 4096 + nb + np * 2;
    float2 v[16];
    float s0 = 0.f, s1 = 0.f, s20 = 0.f, s21 = 0.f;
#pragma unroll
    for (int i = 0; i < 16; i++) {
        float2 f = *(const float2*)(xp + (size_t)i * 4096);
        v[i] = f;
        s0 += f.x; s20 += f.x * f.x;
        s1 += f.y; s21 += f.y * f.y;
    }
    redS[(2 * np) * 17 + cg] = s0;
    redS[(2 * np + 1) * 17 + cg] = s1;
    redS2[(2 * np) * 17 + cg] = s20;
    redS2[(2 * np + 1) * 17 + cg] = s21;
    __syncthreads();
    if (t < 32) {
        float s = 0.f, s2 = 0.f;
#pragma unroll
        for (int g = 0; g < 16; g++) { s += redS[t * 17 + g]; s2 += redS2[t * 17 + g]; }
        float m = s * (1.f / 256.f);
        float var = s2 * (1.f / 256.f) - m * m;
        muv[t] = m;
        rsv[t] = rsqrtf(var + 1e-5f);
    }
    __syncthreads();
    float m0 = muv[2 * np], r0 = rsv[2 * np];
    float m1 = muv[2 * np + 1], r1 = rsv[2 * np + 1];
    u16 hA[16], hB[16];
#pragma unroll
    for (int i = 0; i < 16; i++) {
        float g = gs[cg * 16 + i], e = es[cg * 16 + i];
        float a = (v[i].x - m0) * r0 * g + e;
        float c2 = (v[i].y - m1) * r1 * g + e;
        u16 ha = f2bf(a), hb = f2bf(c2);
        hA[i] = ha; hB[i] = hb;
        xst[(cg * 16 + i) * 17 + np] = (unsigned)ha | ((unsigned)hb << 16);
    }
    // xlnT[b][n][c]: 16 consecutive c per thread per n -> 2x uint4 per n
    {
        u16* dst0 = xlnT + ((size_t)(b * 4096 + nb + 2 * np)) * 256 + cg * 16;
        uint4 qa, qb;
        qa.x = (unsigned)hA[0] | ((unsigned)hA[1] << 16);
        qa.y = (unsigned)hA[2] | ((unsigned)hA[3] << 16);
        qa.z = (unsigned)hA[4] | ((unsigned)hA[5] << 16);
        qa.w = (unsigned)hA[6] | ((unsigned)hA[7] << 16);
        qb.x = (unsigned)hA[8] | ((unsigned)hA[9] << 16);
        qb.y = (unsigned)hA[10] | ((unsigned)hA[11] << 16);
        qb.z = (unsigned)hA[12] | ((unsigned)hA[13] << 16);
        qb.w = (unsigned)hA[14] | ((unsigned)hA[15] << 16);
        *(uint4*)dst0 = qa;
        *(uint4*)(dst0 + 8) = qb;
        u16* dst1 = dst0 + 256;
        qa.x = (unsigned)hB[0] | ((unsigned)hB[1] << 16);
        qa.y = (unsigned)hB[2] | ((unsigned)hB[3] << 16);
        qa.z = (unsigned)hB[4] | ((unsigned)hB[5] << 16);
        qa.w = (unsigned)hB[6] | ((unsigned)hB[7] << 16);
        qb.x = (unsigned)hB[8] | ((unsigned)hB[9] << 16);
        qb.y = (unsigned)hB[10] | ((unsigned)hB[11] << 16);
        qb.z = (unsigned)hB[12] | ((unsigned)hB[13] << 16);
        qb.w = (unsigned)hB[14] | ((unsigned)hB[15] << 16);
        *(uint4*)dst1 = qa;
        *(uint4*)(dst1 + 8) = qb;
    }
    __syncthreads();
    // xcn[b][c][n]: 4 lanes per c-row, 16 B each
#pragma unroll
    for (int j = 0; j < 4; j++) {
        int row = (t >> 2) + j * 64, part = t & 3;
        uint4 q;
        q.x = xst[row * 17 + part * 4 + 0];
        q.y = xst[row * 17 + part * 4 + 1];
        q.z = xst[row * 17 + part * 4 + 2];
        q.w = xst[row * 17 + part * 4 + 3];
        *(uint4*)(xcn + ((size_t)(b * 256 + row)) * 4096 + nb + part * 8) = q;
    }
}

// K2: weight prep. WqkvT[o<512][c]=Wqkv[c][o]; WvTn[c][o]=Wqkv[c][512+o]; WoutT[e][o]=Wout[o][e]
__global__ __launch_bounds__(256) void k_prep(const float* __restrict__ Wqkv,
                                              const float* __restrict__ Wout,
                                              u16* __restrict__ WqkvT, u16* __restrict__ WvTn,
                                              u16* __restrict__ WoutT) {
    int i = blockIdx.x * 256 + threadIdx.x;
    if (i < 512 * 256) { int o = i >> 8, c = i & 255; WqkvT[i] = f2bf(Wqkv[c * 768 + o]); }
    if (i < 256 * 256) {
        int e = i >> 8, o = i & 255;
        WvTn[i] = f2bf(Wqkv[e * 768 + 512 + o]);
        WoutT[i] = f2bf(Wout[o * 256 + e]);
    }
}

// K3: Gram partials. Gp[s][b] = X[tm-panel] . X[tn-panel]^T over n in [s*512, s*512+512)
__global__ __launch_bounds__(256) void k_gram(const u16* __restrict__ xcn, float* __restrict__ Gp) {
    int bid = blockIdx.x;
    int s = bid & 7, tile = (bid >> 3) & 3, b = bid >> 5;
    int tm = tile >> 1, tn = tile & 1;
    __shared__ __align__(16) u16 aT[128 * 32];
    __shared__ __align__(16) u16 bT[128 * 32];
    int t = threadIdx.x, w = t >> 6, lane = t & 63, l15 = lane & 15, quad = lane >> 4;
    int srow = lane >> 2;
    int g8 = (((lane & 3) ^ ((lane >> 3) & 3)) << 3);
    const u16* xb = xcn + (size_t)b * 256 * 4096 + (size_t)s * 512;
    const u16* gA = xb + (size_t)(tm * 128 + w * 32 + srow) * 4096 + g8;
    const u16* gB = xb + (size_t)(tn * 128 + w * 32 + srow) * 4096 + g8;
    u16* lA = aT + w * 1024;
    u16* lB = bT + w * 1024;
    int cOff = ((quad ^ ((l15 >> 1) & 3)) << 3);
    f32x4 acc[2][8];
    f32x4 z = {0.f, 0.f, 0.f, 0.f};
    for (int fm = 0; fm < 2; fm++)
        for (int fn = 0; fn < 8; fn++) acc[fm][fn] = z;
    for (int kt = 0; kt < 16; kt++) {
        int kb = kt * 32;
        if (kt) __syncthreads();
        gload16(gA + kb, lA);
        gload16(gA + 16 * 4096 + kb, lA + 512);
        gload16(gB + kb, lB);
        gload16(gB + 16 * 4096 + kb, lB + 512);
        __syncthreads();
        bf16x8 af0 = *(const bf16x8*)&aT[(w * 32 + l15) * 32 + cOff];
        bf16x8 af1 = *(const bf16x8*)&aT[(w * 32 + 16 + l15) * 32 + cOff];
        for (int fn = 0; fn < 8; fn++) {
            bf16x8 bfr = *(const bf16x8*)&bT[(fn * 16 + l15) * 32 + cOff];
            acc[0][fn] = MFMA(af0, bfr, acc[0][fn]);
            acc[1][fn] = MFMA(af1, bfr, acc[1][fn]);
        }
    }
    float* gp = Gp + (size_t)(s * 16 + b) * 65536;
    for (int fm = 0; fm < 2; fm++)
        for (int fn = 0; fn < 8; fn++)
            for (int r = 0; r < 4; r++) {
                int row = tm * 128 + w * 32 + fm * 16 + quad * 4 + r;
                int col = tn * 128 + fn * 16 + l15;
                gp[row * 256 + col] = acc[fm][fn][r];
            }
}

// K4: G = sum of 8 partials -> hi/lo bf16 split (Ghi + Glo ~= G fp32)
__global__ __launch_bounds__(256) void k_g2b(const float* __restrict__ Gp,
                                             u16* __restrict__ Ghi, u16* __restrict__ Glo) {
    int idx = blockIdx.x * 256 + threadIdx.x;  // < 262144 float4s
    const float4* p = (const float4*)Gp + idx;
    float4 s = p[0];
#pragma unroll
    for (int j = 1; j < 8; j++) {
        float4 v = p[(size_t)j * 262144];
        s.x += v.x; s.y += v.y; s.z += v.z; s.w += v.w;
    }
    u16 h0 = f2bf(s.x), h1 = f2bf(s.y), h2 = f2bf(s.z), h3 = f2bf(s.w);
    u16 l0 = f2bf(s.x - bf2f(h0)), l1 = f2bf(s.y - bf2f(h1));
    u16 l2 = f2bf(s.z - bf2f(h2)), l3 = f2bf(s.w - bf2f(h3));
    uint2 ph; ph.x = (unsigned)h0 | ((unsigned)h1 << 16); ph.y = (unsigned)h2 | ((unsigned)h3 << 16);
    uint2 pl; pl.x = (unsigned)l0 | ((unsigned)l1 << 16); pl.y = (unsigned)l2 | ((unsigned)l3 << 16);
    *(uint2*)(Ghi + (size_t)idx * 4) = ph;
    *(uint2*)(Glo + (size_t)idx * 4) = pl;
}

// K5: Sq = Wqk (512x256) . (Ghi + Glo), hi/lo output. grid = 16*8 = 128
__global__ __launch_bounds__(256) void k_sq(const u16* __restrict__ A,
                                            const u16* __restrict__ Ghi, const u16* __restrict__ Glo,
                                            u16* __restrict__ Shi, u16* __restrict__ Slo) {
    __shared__ __align__(16) u16 aT[128 * 32];
    __shared__ __align__(16) u16 bT[128 * 32];
    int bid = blockIdx.x;
    int b = bid >> 3;
    int r2 = bid & 7;
    int mbase = (r2 >> 1) * 128, nbase = (r2 & 1) * 128;
    int t = threadIdx.x, w = t >> 6, lane = t & 63, l15 = lane & 15, quad = lane >> 4;
    int srow = lane >> 2;
    int g8 = (((lane & 3) ^ ((lane >> 3) & 3)) << 3);
    const u16* gA = A + (size_t)(mbase + w * 32 + srow) * 256 + g8;
    const u16* gBh = Ghi + (size_t)b * 65536 + (size_t)(nbase + w * 32 + srow) * 256 + g8;
    const u16* gBl = Glo + (size_t)b * 65536 + (size_t)(nbase + w * 32 + srow) * 256 + g8;
    u16* lA = aT + w * 1024;
    u16* lB = bT + w * 1024;
    int cOff = ((quad ^ ((l15 >> 1) & 3)) << 3);
    f32x4 acc[2][8];
    f32x4 z = {0.f, 0.f, 0.f, 0.f};
    for (int fm = 0; fm < 2; fm++)
        for (int fn = 0; fn < 8; fn++) acc[fm][fn] = z;
    for (int kt = 0; kt < 16; kt++) {
        int kb = (kt & 7) * 32;
        const u16* gB = (kt < 8) ? gBh : gBl;
        if (kt) __syncthreads();
        gload16(gA + kb, lA);
        gload16(gA + 16 * 256 + kb, lA + 512);
        gload16(gB + kb, lB);
        gload16(gB + 16 * 256 + kb, lB + 512);
        __syncthreads();
        bf16x8 af0 = *(const bf16x8*)&aT[(w * 32 + l15) * 32 + cOff];
        bf16x8 af1 = *(const bf16x8*)&aT[(w * 32 + 16 + l15) * 32 + cOff];
        for (int fn = 0; fn < 8; fn++) {
            bf16x8 bfr = *(const bf16x8*)&bT[(fn * 16 + l15) * 32 + cOff];
            acc[0][fn] = MFMA(af0, bfr, acc[0][fn]);
            acc[1][fn] = MFMA(af1, bfr, acc[1][fn]);
        }
    }
    for (int fm = 0; fm < 2; fm++)
        for (int fn = 0; fn < 8; fn++)
            for (int r = 0; r < 4; r++) {
                int row = mbase + w * 32 + fm * 16 + quad * 4 + r;
                int col = nbase + fn * 16 + l15;
                float v = acc[fm][fn][r];
                u16 hi = f2bf(v);
                Shi[((size_t)b * 512 + row) * 256 + col] = hi;
                Slo[((size_t)b * 512 + row) * 256 + col] = f2bf(v - bf2f(hi));
            }
}

// K6: generic 128x128-tile GEMM, K=256: C[m][col] = sum_k A[m][k]*B[col][k]
// mode 0: bf16 out; mode 1: fp32 + bias
__global__ __launch_bounds__(256) void k_gemm(const u16* __restrict__ A, size_t aStrB,
                                              const u16* __restrict__ Bb, size_t bStrB,
                                              int mtiles, int ntiles,
                                              u16* __restrict__ o16, float* __restrict__ o32,
                                              const float* __restrict__ bias,
                                              size_t oStrB, int oRstr, int mode) {
    __shared__ __align__(16) u16 aT[128 * 32];
    __shared__ __align__(16) u16 bT[128 * 32];
    int bid = blockIdx.x;
    int per_b = mtiles * ntiles;
    int b = bid / per_b;
    int r2 = bid % per_b;
    int mbase = (r2 / ntiles) * 128, nbase = (r2 % ntiles) * 128;
    int t = threadIdx.x, w = t >> 6, lane = t & 63, l15 = lane & 15, quad = lane >> 4;
    const u16* Ap = A + (size_t)b * aStrB;
    const u16* Bp = Bb + (size_t)b * bStrB;
    int srow = lane >> 2;
    int g8 = (((lane & 3) ^ ((lane >> 3) & 3)) << 3);
    const u16* gA = Ap + (size_t)(mbase + w * 32 + srow) * 256 + g8;
    const u16* gB = Bp + (size_t)(nbase + w * 32 + srow) * 256 + g8;
    u16* lA = aT + w * 1024;
    u16* lB = bT + w * 1024;
    int cOff = ((quad ^ ((l15 >> 1) & 3)) << 3);
    f32x4 acc[2][8];
    f32x4 z = {0.f, 0.f, 0.f, 0.f};
    for (int fm = 0; fm < 2; fm++)
        for (int fn = 0; fn < 8; fn++) acc[fm][fn] = z;
    for (int kt = 0; kt < 8; kt++) {
        int kb = kt * 32;
        if (kt) __syncthreads();
        gload16(gA + kb, lA);
        gload16(gA + 16 * 256 + kb, lA + 512);
        gload16(gB + kb, lB);
        gload16(gB + 16 * 256 + kb, lB + 512);
        __syncthreads();
        bf16x8 af0 = *(const bf16x8*)&aT[(w * 32 + l15) * 32 + cOff];
        bf16x8 af1 = *(const bf16x8*)&aT[(w * 32 + 16 + l15) * 32 + cOff];
        for (int fn = 0; fn < 8; fn++) {
            bf16x8 bfr = *(const bf16x8*)&bT[(fn * 16 + l15) * 32 + cOff];
            acc[0][fn] = MFMA(af0, bfr, acc[0][fn]);
            acc[1][fn] = MFMA(af1, bfr, acc[1][fn]);
        }
    }
    if (mode == 0) {
        for (int fm = 0; fm < 2; fm++)
            for (int fn = 0; fn < 8; fn++)
                for (int r = 0; r < 4; r++) {
                    int row = mbase + w * 32 + fm * 16 + quad * 4 + r;
                    int col = nbase + fn * 16 + l15;
                    o16[(size_t)b * oStrB + (size_t)row * oRstr + col] = f2bf(acc[fm][fn][r]);
                }
    } else {
        for (int fm = 0; fm < 2; fm++)
            for (int fn = 0; fn < 8; fn++)
                for (int r = 0; r < 4; r++) {
                    int row = mbase + w * 32 + fm * 16 + quad * 4 + r;
                    int col = nbase + fn * 16 + l15;
                    o32[(size_t)b * oStrB + (size_t)row * oRstr + col] = acc[fm][fn][r] + bias[row];
                }
    }
}

// K7: per (b,h): sim = (Sq_hi+Sq_lo) . Wk^T (MFMA), norms from diag, softmax, M_h = wo.attn
// grid = 128 (b*8+h), block 256
__global__ __launch_bounds__(256) void k_attn(const u16* __restrict__ Shi,
                                              const u16* __restrict__ Slo,
                                              const u16* __restrict__ WqkvT,
                                              const u16* __restrict__ WoutT,
                                              const float* __restrict__ temp,
                                              u16* __restrict__ M_all) {
    int bh = blockIdx.x;
    int b = bh >> 3, h = bh & 7;
    __shared__ u16 sqh[32 * 264], sql[32 * 264], skh[32 * 264], wq[32 * 264], wk[32 * 264];
    __shared__ u16 wo[256 * 40];
    __shared__ u16 attnT[32 * 40];
    __shared__ float simS[32 * 33];
    __shared__ float redn[4 * 64];
    __shared__ float scq[32], sck[32];
    int t = threadIdx.x, w = t >> 6, lane = t & 63, l15 = lane & 15, quad = lane >> 4;
    {
        int r = t >> 3, cc0 = (t & 7) * 32;
        const u16* gqh = Shi + ((size_t)(b * 512) + h * 32 + r) * 256 + cc0;
        const u16* gql = Slo + ((size_t)(b * 512) + h * 32 + r) * 256 + cc0;
        const u16* gkh = Shi + ((size_t)(b * 512) + 256 + h * 32 + r) * 256 + cc0;
        const u16* gwq = WqkvT + (size_t)(h * 32 + r) * 256 + cc0;
        const u16* gwk = WqkvT + (size_t)(256 + h * 32 + r) * 256 + cc0;
#pragma unroll
        for (int k = 0; k < 4; k++) {
            *(uint4*)&sqh[r * 264 + cc0 + k * 8] = *(const uint4*)(gqh + k * 8);
            *(uint4*)&sql[r * 264 + cc0 + k * 8] = *(const uint4*)(gql + k * 8);
            *(uint4*)&skh[r * 264 + cc0 + k * 8] = *(const uint4*)(gkh + k * 8);
            *(uint4*)&wq[r * 264 + cc0 + k * 8] = *(const uint4*)(gwq + k * 8);
            *(uint4*)&wk[r * 264 + cc0 + k * 8] = *(const uint4*)(gwk + k * 8);
        }
        const u16* gwo = WoutT + (size_t)t * 256 + h * 32;
#pragma unroll
        for (int k = 0; k < 4; k++) *(uint4*)&wo[t * 40 + k * 8] = *(const uint4*)(gwo + k * 8);
    }
    __syncthreads();
    // norms: |q_i|^2 = (Wq G)[i].Wq[i] ; |k_j|^2 = (Wk G)[j].Wk[j]
    {
        int rn = t & 63, cc = t >> 6;
        int e0 = cc * 64;
        float s = 0.f;
        if (rn < 32) {
            const u16* ph = &sqh[rn * 264];
            const u16* pl = &sql[rn * 264];
            const u16* pb = &wq[rn * 264];
            for (int e = 0; e < 64; e++)
                s += (bf2f(ph[e0 + e]) + bf2f(pl[e0 + e])) * bf2f(pb[e0 + e]);
        } else {
            const u16* ph = &skh[(rn - 32) * 264];
            const u16* pb = &wk[(rn - 32) * 264];
            for (int e = 0; e < 64; e++)
                s += bf2f(ph[e0 + e]) * bf2f(pb[e0 + e]);
        }
        redn[cc * 64 + rn] = s;
    }
    // sim MFMA: A = Sq rows (hi then lo), B = Wk WEIGHT rows  -> sim = Wq.G.Wk^T
    {
        int iq = w >> 1, jq = w & 1;
        f32x4 acc = {0.f, 0.f, 0.f, 0.f};
        for (int s8 = 0; s8 < 8; s8++) {
            bf16x8 a = *(const bf16x8*)&sqh[(iq * 16 + l15) * 264 + s8 * 32 + quad * 8];
            bf16x8 bb = *(const bf16x8*)&wk[(jq * 16 + l15) * 264 + s8 * 32 + quad * 8];
            acc = MFMA(a, bb, acc);
        }
        for (int s8 = 0; s8 < 8; s8++) {
            bf16x8 a = *(const bf16x8*)&sql[(iq * 16 + l15) * 264 + s8 * 32 + quad * 8];
            bf16x8 bb = *(const bf16x8*)&wk[(jq * 16 + l15) * 264 + s8 * 32 + quad * 8];
            acc = MFMA(a, bb, acc);
        }
        for (int r = 0; r < 4; r++)
            simS[(iq * 16 + quad * 4 + r) * 33 + jq * 16 + l15] = acc[r];
    }
    __syncthreads();
    if (t < 32)
        scq[t] = expf(temp[h]) * 8.0f /
                 fmaxf(sqrtf(redn[t] + redn[64 + t] + redn[128 + t] + redn[192 + t]), 1e-12f);
    else if (t < 64) {
        int d = t - 32;
        sck[d] = 1.0f / fmaxf(sqrtf(redn[32 + d] + redn[96 + d] + redn[160 + d] + redn[224 + d]), 1e-12f);
    }
    __syncthreads();
    if (t < 32) {
        float row[32];
        float m = -1e30f, sqv = scq[t];
#pragma unroll
        for (int j = 0; j < 32; j++) {
            float v = simS[t * 33 + j] * sqv * sck[j];
            row[j] = v; m = fmaxf(m, v);
        }
        float s = 0.f;
#pragma unroll
        for (int j = 0; j < 32; j++) { float p = expf(row[j] - m); row[j] = p; s += p; }
        float inv = 1.f / s;
#pragma unroll
        for (int j = 0; j < 32; j++) attnT[j * 40 + t] = f2bf(row[j] * inv);  // attnT[j][i]
    }
    __syncthreads();
    // M_h[c][j] = sum_d wo[c][d] attn[d][j]
    {
        f32x4 z = {0.f, 0.f, 0.f, 0.f};
        for (int mf = 0; mf < 4; mf++) {
            bf16x8 a = *(const bf16x8*)&wo[((w * 4 + mf) * 16 + l15) * 40 + quad * 8];
            for (int nf = 0; nf < 2; nf++) {
                bf16x8 bb = *(const bf16x8*)&attnT[(nf * 16 + l15) * 40 + quad * 8];
                f32x4 d = MFMA(a, bb, z);
                for (int r = 0; r < 4; r++) {
                    int c = (w * 4 + mf) * 16 + quad * 4 + r;
                    M_all[((size_t)(b * 256) + c) * 256 + h * 32 + nf * 16 + l15] = f2bf(d[r]);
                }
            }
        }
    }
}

extern "C" void kernel_launch(void* const* d_in, const int* in_sizes, int n_in,
                              void* d_out, int out_size, void* d_ws, size_t ws_size,
                              hipStream_t stream) {
    const float* x     = (const float*)d_in[0];
    const float* gamma = (const float*)d_in[1];
    const float* beta  = (const float*)d_in[2];
    const float* Wqkv  = (const float*)d_in[3];
    const float* temp  = (const float*)d_in[4];
    const float* Wout  = (const float*)d_in[5];
    const float* bout  = (const float*)d_in[6];
    float* out = (float*)d_out;

    char* ws = (char*)d_ws;
    size_t off = 0;
    auto alloc = [&](size_t nbytes) -> void* {
        void* p = ws + off;
        off = (off + nbytes + 255) & ~(size_t)255;
        return p;
    };
    u16* xlnT   = (u16*)alloc((size_t)16 * 4096 * 256 * 2);   // 32 MB (b,n,c)
    u16* xcn    = (u16*)alloc((size_t)16 * 256 * 4096 * 2);   // 32 MB (b,c,n)
    u16* WqkvT  = (u16*)alloc((size_t)512 * 256 * 2);
    u16* WvTn   = (u16*)alloc((size_t)256 * 256 * 2);
    u16* WoutT  = (u16*)alloc((size_t)256 * 256 * 2);
    float* Gp   = (float*)alloc((size_t)8 * 16 * 65536 * 4);  // 32 MB
    u16* Gbh    = (u16*)alloc((size_t)16 * 65536 * 2);        // 2 MB
    u16* Gbl    = (u16*)alloc((size_t)16 * 65536 * 2);        // 2 MB
    u16* Sqh    = (u16*)alloc((size_t)16 * 512 * 256 * 2);    // 4 MB
    u16* Sql    = (u16*)alloc((size_t)16 * 512 * 256 * 2);    // 4 MB
    u16* M_all  = (u16*)alloc((size_t)16 * 256 * 256 * 2);    // 2 MB
    u16* F      = (u16*)alloc((size_t)16 * 256 * 256 * 2);    // 2 MB
    (void)ws_size; (void)in_sizes; (void)n_in; (void)out_size;

    hipLaunchKernelGGL(k_ln, dim3(2048), dim3(256), 0, stream, x, gamma, beta, xlnT, xcn);
    hipLaunchKernelGGL(k_prep, dim3(768), dim3(256), 0, stream, Wqkv, Wout, WqkvT, WvTn, WoutT);
    hipLaunchKernelGGL(k_gram, dim3(512), dim3(256), 0, stream, xcn, Gp);
    hipLaunchKernelGGL(k_g2b, dim3(1024), dim3(256), 0, stream, Gp, Gbh, Gbl);
    hipLaunchKernelGGL(k_sq, dim3(128), dim3(256), 0, stream, WqkvT, Gbh, Gbl, Sqh, Sql);
    hipLaunchKernelGGL(k_attn, dim3(128), dim3(256), 0, stream, Sqh, Sql, WqkvT, WoutT, temp, M_all);
    // F[b] = M_b (256x256) . Wv  (B-rows = WvTn rows, i.e. F = M.Wv^T in hj)
    hipLaunchKernelGGL(k_gemm, dim3(64), dim3(256), 0, stream,
                       M_all, (size_t)65536, WvTn, (size_t)0, 2, 2,
                       F, (float*)nullptr, (const float*)nullptr,
                       (size_t)65536, 256, 0);
    // out[b] = F_b (256x256) . X_b  (+bias): B-rows = xlnT rows (n,c)
    hipLaunchKernelGGL(k_gemm, dim3(1024), dim3(256), 0, stream,
                       F, (size_t)65536, xlnT, (size_t)4096 * 256, 2, 32,
                       (u16*)nullptr, out, bout,
                       (size_t)256 * 4096, 4096, 1);
}